// Round 5
// baseline (3370.871 us; speedup 1.0000x reference)
//
#include <hip/hip_runtime.h>
#include <cstddef>

#define EN 800000
#define VN 50000

// Forced-VMEM broadcast loads: opaque VGPR zero in the address defeats
// uniformity analysis, so the compiler emits global_load_dwordx4 (vmcnt,
// counted, pipelineable) instead of s_load (SMEM: out-of-order returns
// force lgkmcnt(0) drains -> no pipelining).
__device__ __forceinline__ float4 ld4(const float* p, int z) {
    return *(const float4*)(p + z);
}
__device__ __forceinline__ float ld1(const float* p, int z) {
    return p[z];
}

// =====================================================================
// node_pre:
//   A[v][j]      = s[v] @ Ws1[0:64]      B[v][j] = s[v] @ Ws1[64:128]
//   VA[v][h*3+r] = V[v] @ Wh1[0:8]       VB      = V[v] @ Wh1[8:16]   (h-major)
// =====================================================================
__global__ __launch_bounds__(256) void node_pre(
    const float* __restrict__ s, const float* __restrict__ V,
    const float* __restrict__ Wh1, const float* __restrict__ Ws1,
    float* __restrict__ A, float* __restrict__ B,
    float* __restrict__ VA, float* __restrict__ VB)
{
    const int tid  = threadIdx.x;
    const int lane = tid & 63;
    const int wv   = __builtin_amdgcn_readfirstlane(tid >> 6);

    float w[128];
    #pragma unroll
    for (int k = 0; k < 128; ++k) w[k] = Ws1[k * 64 + lane];

    const int hv = (lane < 51) ? (lane / 3) : 0;
    const int rv = (lane < 51) ? (lane % 3) : 0;
    float whA[8], whB[8];
    #pragma unroll
    for (int d = 0; d < 8; ++d) {
        whA[d] = Wh1[d * 17 + hv];
        whB[d] = Wh1[(8 + d) * 17 + hv];
    }

    const int nwaves = gridDim.x * 4;
    for (int v = blockIdx.x * 4 + wv; v < VN; v += nwaves) {
        const float* sv = s + (size_t)v * 64;
        float a = 0.f, b = 0.f;
        #pragma unroll
        for (int k = 0; k < 64; ++k) {
            float sk = sv[k];
            a += sk * w[k];
            b += sk * w[64 + k];
        }
        A[(size_t)v * 64 + lane] = a;
        B[(size_t)v * 64 + lane] = b;

        const float* vrow = V + (size_t)v * 24 + rv * 8;
        float va = 0.f, vb = 0.f;
        #pragma unroll
        for (int d = 0; d < 8; ++d) {
            float x = vrow[d];
            va += x * whA[d];
            vb += x * whB[d];
        }
        if (lane < 51) {
            VA[(size_t)v * 52 + lane] = va;
            VB[(size_t)v * 52 + lane] = vb;
        }
    }
}

// =====================================================================
// edge_kernel: one thread per edge, ZERO LDS.
//  - All weight reads: forced-VMEM broadcast (ld4/ld1 with opaque z).
//  - Inter-layer 64-float s-vector lives in the d_out s3 region ([e][64],
//    coalesced float4 stores; read back as float4 per 4-row chunk - the
//    L2 holds it, reuse distance ~1us).
//  - Short row groups (s_e 16, vn 17, vn2 8, gates) statically unrolled
//    with multiplicands in registers.
// =====================================================================
__global__ __launch_bounds__(256, 3) void edge_kernel(
    const float* __restrict__ s_e, const float* __restrict__ V_e,
    const int* __restrict__ eidx,
    const float* __restrict__ Wh1, const float* __restrict__ Ws1, const float* __restrict__ bs1,
    const float* __restrict__ Wmu1, const float* __restrict__ Wg1, const float* __restrict__ bg1,
    const float* __restrict__ Wh2, const float* __restrict__ Ws2, const float* __restrict__ bs2,
    const float* __restrict__ Wmu2, const float* __restrict__ Wg2, const float* __restrict__ bg2,
    const float* __restrict__ Wh3, const float* __restrict__ Ws3, const float* __restrict__ bs3,
    const float* __restrict__ Wmu3, const float* __restrict__ Wg3, const float* __restrict__ bg3,
    const float* __restrict__ A, const float* __restrict__ B,
    const float* __restrict__ VA, const float* __restrict__ VB,
    float* __restrict__ out)
{
    int z;
    asm volatile("v_mov_b32 %0, 0" : "=v"(z));   // opaque zero (VGPR)

    const int tid = threadIdx.x;
    const int e   = blockIdx.x * 256 + tid;
    const int src = eidx[e];
    const int dst = eidx[EN + e];

    // ---------------- Layer 1: vector path ----------------
    const float ve0 = V_e[(size_t)e * 3 + 0];
    const float ve1 = V_e[(size_t)e * 3 + 1];
    const float ve2 = V_e[(size_t)e * 3 + 2];

    // Wh1 row 16 (17 floats, 1088B offset -> 16B aligned)
    float wv16[17];
    {
        const float* p = Wh1 + 16 * 17;
        #pragma unroll
        for (int q = 0; q < 4; ++q) {
            float4 t = ld4(p + 4 * q, z);
            wv16[4*q] = t.x; wv16[4*q+1] = t.y; wv16[4*q+2] = t.z; wv16[4*q+3] = t.w;
        }
        wv16[16] = ld1(p + 16, z);
    }

    float vn[17];
    float vmu[24];
    #pragma unroll
    for (int o = 0; o < 24; ++o) vmu[o] = 0.f;

    const float4* qa = (const float4*)(VA + (size_t)src * 52);
    const float4* qb = (const float4*)(VB + (size_t)dst * 52);

    #pragma unroll
    for (int c = 0; c < 4; ++c) {          // h = 4c .. 4c+3 (h-major chunks)
        float4 a0 = qa[3*c], a1 = qa[3*c+1], a2 = qa[3*c+2];
        float4 b0 = qb[3*c], b1 = qb[3*c+1], b2 = qb[3*c+2];
        float av[12] = {a0.x,a0.y,a0.z,a0.w, a1.x,a1.y,a1.z,a1.w, a2.x,a2.y,a2.z,a2.w};
        float bv[12] = {b0.x,b0.y,b0.z,b0.w, b1.x,b1.y,b1.z,b1.w, b2.x,b2.y,b2.z,b2.w};
        #pragma unroll
        for (int i = 0; i < 4; ++i) {
            const int h = 4*c + i;
            float ww = wv16[h];
            float v0 = av[3*i+0] + bv[3*i+0] + ve0 * ww;
            float v1 = av[3*i+1] + bv[3*i+1] + ve1 * ww;
            float v2 = av[3*i+2] + bv[3*i+2] + ve2 * ww;
            vn[h] = sqrtf(v0*v0 + v1*v1 + v2*v2 + 1e-8f);
            float4 m0 = ld4(Wmu1 + h * 8, z);
            float4 m1 = ld4(Wmu1 + h * 8 + 4, z);
            vmu[0]  += v0*m0.x; vmu[1]  += v0*m0.y; vmu[2]  += v0*m0.z; vmu[3]  += v0*m0.w;
            vmu[4]  += v0*m1.x; vmu[5]  += v0*m1.y; vmu[6]  += v0*m1.z; vmu[7]  += v0*m1.w;
            vmu[8]  += v1*m0.x; vmu[9]  += v1*m0.y; vmu[10] += v1*m0.z; vmu[11] += v1*m0.w;
            vmu[12] += v1*m1.x; vmu[13] += v1*m1.y; vmu[14] += v1*m1.z; vmu[15] += v1*m1.w;
            vmu[16] += v2*m0.x; vmu[17] += v2*m0.y; vmu[18] += v2*m0.z; vmu[19] += v2*m0.w;
            vmu[20] += v2*m1.x; vmu[21] += v2*m1.y; vmu[22] += v2*m1.z; vmu[23] += v2*m1.w;
        }
    }
    {   // h = 16 (VA/VB elements 48..50; 51 is pad)
        float4 a = qa[12], b = qb[12];
        float ww = wv16[16];
        float v0 = a.x + b.x + ve0 * ww;
        float v1 = a.y + b.y + ve1 * ww;
        float v2 = a.z + b.z + ve2 * ww;
        vn[16] = sqrtf(v0*v0 + v1*v1 + v2*v2 + 1e-8f);
        float4 m0 = ld4(Wmu1 + 16 * 8, z);
        float4 m1 = ld4(Wmu1 + 16 * 8 + 4, z);
        vmu[0]  += v0*m0.x; vmu[1]  += v0*m0.y; vmu[2]  += v0*m0.z; vmu[3]  += v0*m0.w;
        vmu[4]  += v0*m1.x; vmu[5]  += v0*m1.y; vmu[6]  += v0*m1.z; vmu[7]  += v0*m1.w;
        vmu[8]  += v1*m0.x; vmu[9]  += v1*m0.y; vmu[10] += v1*m0.z; vmu[11] += v1*m0.w;
        vmu[12] += v1*m1.x; vmu[13] += v1*m1.y; vmu[14] += v1*m1.z; vmu[15] += v1*m1.w;
        vmu[16] += v2*m0.x; vmu[17] += v2*m0.y; vmu[18] += v2*m0.z; vmu[19] += v2*m0.w;
        vmu[20] += v2*m1.x; vmu[21] += v2*m1.y; vmu[22] += v2*m1.z; vmu[23] += v2*m1.w;
    }

    // ---------------- Layer 1: scalar path ----------------
    float acc[64];
    {
        const float4* fa = (const float4*)(A + (size_t)src * 64);
        const float4* fb = (const float4*)(B + (size_t)dst * 64);
        #pragma unroll
        for (int q = 0; q < 16; ++q) {
            float4 ta = fa[q], tb = fb[q];
            float4 bb = ld4(bs1 + 4 * q, z);
            acc[4*q+0] = ta.x + tb.x + bb.x;
            acc[4*q+1] = ta.y + tb.y + bb.y;
            acc[4*q+2] = ta.z + tb.z + bb.z;
            acc[4*q+3] = ta.w + tb.w + bb.w;
        }
    }
    // s_e rows (16, static; m per-lane coalesced float4)
    {
        const float4* ps = (const float4*)(s_e + (size_t)e * 16);
        float4 e0 = ps[0], e1 = ps[1], e2 = ps[2], e3 = ps[3];
        float mm[16] = {e0.x,e0.y,e0.z,e0.w, e1.x,e1.y,e1.z,e1.w,
                        e2.x,e2.y,e2.z,e2.w, e3.x,e3.y,e3.z,e3.w};
        #pragma unroll
        for (int k = 0; k < 16; ++k) {
            const float* wr = Ws1 + (128 + k) * 64;
            float m = mm[k];
            #pragma unroll
            for (int q = 0; q < 16; ++q) {
                float4 w = ld4(wr + 4 * q, z);
                acc[4*q+0] += m * w.x; acc[4*q+1] += m * w.y;
                acc[4*q+2] += m * w.z; acc[4*q+3] += m * w.w;
            }
        }
    }
    // vn rows (17, static)
    #pragma unroll
    for (int k = 0; k < 17; ++k) {
        const float* wr = Ws1 + (144 + k) * 64;
        float m = vn[k];
        #pragma unroll
        for (int q = 0; q < 16; ++q) {
            float4 w = ld4(wr + 4 * q, z);
            acc[4*q+0] += m * w.x; acc[4*q+1] += m * w.y;
            acc[4*q+2] += m * w.z; acc[4*q+3] += m * w.w;
        }
    }

    // gate1 + vector gating; then store relu(acc) -> scratch (out s3 region)
    float Vv[24];
    {
        float g[8];
        float4 b0 = ld4(bg1, z), b1 = ld4(bg1 + 4, z);
        g[0]=b0.x; g[1]=b0.y; g[2]=b0.z; g[3]=b0.w;
        g[4]=b1.x; g[5]=b1.y; g[6]=b1.z; g[7]=b1.w;
        #pragma unroll
        for (int j = 0; j < 64; ++j) {
            float sj = acc[j];
            float4 wa = ld4(Wg1 + j * 8, z), wb = ld4(Wg1 + j * 8 + 4, z);
            g[0] += sj*wa.x; g[1] += sj*wa.y; g[2] += sj*wa.z; g[3] += sj*wa.w;
            g[4] += sj*wb.x; g[5] += sj*wb.y; g[6] += sj*wb.z; g[7] += sj*wb.w;
        }
        #pragma unroll
        for (int o = 0; o < 8; ++o) {
            float gg = 1.f / (1.f + __expf(-g[o]));
            Vv[o] = vmu[o]*gg; Vv[8+o] = vmu[8+o]*gg; Vv[16+o] = vmu[16+o]*gg;
        }
    }
    float* soS = out + (size_t)e * 64;     // scratch = final-s3 region
    #pragma unroll
    for (int q = 0; q < 16; ++q) {
        float4 t;
        t.x = fmaxf(acc[4*q+0], 0.f); t.y = fmaxf(acc[4*q+1], 0.f);
        t.z = fmaxf(acc[4*q+2], 0.f); t.w = fmaxf(acc[4*q+3], 0.f);
        ((float4*)soS)[q] = t;
    }

    // ---------------- Layers 2 & 3 ----------------
    #pragma unroll 1
    for (int t = 0; t < 2; ++t) {
        const float* Wh  = t ? Wh3  : Wh2;
        const float* Ws  = t ? Ws3  : Ws2;
        const float* bs  = t ? bs3  : bs2;
        const float* Wmu = t ? Wmu3 : Wmu2;
        const float* Wg  = t ? Wg3  : Wg2;
        const float* bg  = t ? bg3  : bg2;

        // vector path: Wh/Wmu bulk into regs (static use), vn2+vmu2
        float whv[64], wmv[64];
        #pragma unroll
        for (int q = 0; q < 16; ++q) {
            float4 a = ld4(Wh + 4 * q, z);
            whv[4*q]=a.x; whv[4*q+1]=a.y; whv[4*q+2]=a.z; whv[4*q+3]=a.w;
            float4 b = ld4(Wmu + 4 * q, z);
            wmv[4*q]=b.x; wmv[4*q+1]=b.y; wmv[4*q+2]=b.z; wmv[4*q+3]=b.w;
        }
        float vn2[8];
        float vmu2[24];
        #pragma unroll
        for (int o = 0; o < 24; ++o) vmu2[o] = 0.f;
        #pragma unroll
        for (int h = 0; h < 8; ++h) {
            float v0 = 0.f, v1 = 0.f, v2 = 0.f;
            #pragma unroll
            for (int d = 0; d < 8; ++d) {
                float wd = whv[d * 8 + h];
                v0 += Vv[d]*wd; v1 += Vv[8+d]*wd; v2 += Vv[16+d]*wd;
            }
            vn2[h] = sqrtf(v0*v0 + v1*v1 + v2*v2 + 1e-8f);
            #pragma unroll
            for (int o = 0; o < 8; ++o) {
                float m = wmv[h * 8 + o];
                vmu2[o] += v0*m; vmu2[8+o] += v1*m; vmu2[16+o] += v2*m;
            }
        }

        // acc init
        float acc2[64];
        #pragma unroll
        for (int q = 0; q < 16; ++q) {
            float4 bb = ld4(bs + 4 * q, z);
            acc2[4*q]=bb.x; acc2[4*q+1]=bb.y; acc2[4*q+2]=bb.z; acc2[4*q+3]=bb.w;
        }
        // main 64 rows: m from scratch (float4 per 4-row chunk, vmcnt)
        #pragma unroll 1
        for (int c = 0; c < 16; ++c) {
            float4 mv = *(const float4*)(soS + 4 * c);
            const float* wr = Ws + (4 * c) * 64;
            float m4[4] = {mv.x, mv.y, mv.z, mv.w};
            #pragma unroll
            for (int i = 0; i < 4; ++i) {
                float m = m4[i];
                const float* wri = wr + i * 64;
                #pragma unroll
                for (int q = 0; q < 16; ++q) {
                    float4 w = ld4(wri + 4 * q, z);
                    acc2[4*q+0] += m * w.x; acc2[4*q+1] += m * w.y;
                    acc2[4*q+2] += m * w.z; acc2[4*q+3] += m * w.w;
                }
            }
        }
        // vn2 rows (8, static)
        #pragma unroll
        for (int k = 0; k < 8; ++k) {
            const float* wr = Ws + (64 + k) * 64;
            float m = vn2[k];
            #pragma unroll
            for (int q = 0; q < 16; ++q) {
                float4 w = ld4(wr + 4 * q, z);
                acc2[4*q+0] += m * w.x; acc2[4*q+1] += m * w.y;
                acc2[4*q+2] += m * w.z; acc2[4*q+3] += m * w.w;
            }
        }

        // gate + vector gating
        float g[8];
        {
            float4 b0 = ld4(bg, z), b1 = ld4(bg + 4, z);
            g[0]=b0.x; g[1]=b0.y; g[2]=b0.z; g[3]=b0.w;
            g[4]=b1.x; g[5]=b1.y; g[6]=b1.z; g[7]=b1.w;
        }
        #pragma unroll
        for (int j = 0; j < 64; ++j) {
            float sj = acc2[j];
            float4 wa = ld4(Wg + j * 8, z), wb = ld4(Wg + j * 8 + 4, z);
            g[0] += sj*wa.x; g[1] += sj*wa.y; g[2] += sj*wa.z; g[3] += sj*wa.w;
            g[4] += sj*wb.x; g[5] += sj*wb.y; g[6] += sj*wb.z; g[7] += sj*wb.w;
        }
        #pragma unroll
        for (int o = 0; o < 8; ++o) {
            float gg = 1.f / (1.f + __expf(-g[o]));
            Vv[o] = vmu2[o]*gg; Vv[8+o] = vmu2[8+o]*gg; Vv[16+o] = vmu2[16+o]*gg;
        }

        if (t == 0) {
            #pragma unroll
            for (int q = 0; q < 16; ++q) {
                float4 tq;
                tq.x = fmaxf(acc2[4*q+0], 0.f); tq.y = fmaxf(acc2[4*q+1], 0.f);
                tq.z = fmaxf(acc2[4*q+2], 0.f); tq.w = fmaxf(acc2[4*q+3], 0.f);
                ((float4*)soS)[q] = tq;
            }
        } else {
            // final s3 (no relu) - same region
            #pragma unroll
            for (int q = 0; q < 16; ++q) {
                float4 tq;
                tq.x = acc2[4*q+0]; tq.y = acc2[4*q+1];
                tq.z = acc2[4*q+2]; tq.w = acc2[4*q+3];
                ((float4*)soS)[q] = tq;
            }
        }
    }

    // final V3 [E,3,8]
    float4* pv = (float4*)(out + (size_t)EN * 64 + (size_t)e * 24);
    #pragma unroll
    for (int q = 0; q < 6; ++q) {
        float4 tq; tq.x = Vv[4*q]; tq.y = Vv[4*q+1]; tq.z = Vv[4*q+2]; tq.w = Vv[4*q+3];
        pv[q] = tq;
    }
}

extern "C" void kernel_launch(void* const* d_in, const int* in_sizes, int n_in,
                              void* d_out, int out_size, void* d_ws, size_t ws_size,
                              hipStream_t stream)
{
    const float* s    = (const float*)d_in[0];
    const float* V    = (const float*)d_in[1];
    const float* s_e  = (const float*)d_in[2];
    const float* V_e  = (const float*)d_in[3];
    const int*   eidx = (const int*)d_in[4];
    const float* Wh1 = (const float*)d_in[5];
    const float* Ws1 = (const float*)d_in[6];
    const float* bs1 = (const float*)d_in[7];
    const float* Wmu1= (const float*)d_in[8];
    const float* Wg1 = (const float*)d_in[9];
    const float* bg1 = (const float*)d_in[10];
    const float* Wh2 = (const float*)d_in[11];
    const float* Ws2 = (const float*)d_in[12];
    const float* bs2 = (const float*)d_in[13];
    const float* Wmu2= (const float*)d_in[14];
    const float* Wg2 = (const float*)d_in[15];
    const float* bg2 = (const float*)d_in[16];
    const float* Wh3 = (const float*)d_in[17];
    const float* Ws3 = (const float*)d_in[18];
    const float* bs3 = (const float*)d_in[19];
    const float* Wmu3= (const float*)d_in[20];
    const float* Wg3 = (const float*)d_in[21];
    const float* bg3 = (const float*)d_in[22];

    float* ws  = (float*)d_ws;
    float* A   = ws;                      // 50000*64
    float* B   = A + 3200000;             // 50000*64
    float* VA  = B + 3200000;             // 50000*52 (h-major, padded)
    float* VB  = VA + 2600000;            // 50000*52
    float* out = (float*)d_out;

    hipLaunchKernelGGL(node_pre, dim3(512), dim3(256), 0, stream,
                       s, V, Wh1, Ws1, A, B, VA, VB);
    hipLaunchKernelGGL(edge_kernel, dim3(EN / 256), dim3(256), 0, stream,
                       s_e, V_e, eidx,
                       Wh1, Ws1, bs1, Wmu1, Wg1, bg1,
                       Wh2, Ws2, bs2, Wmu2, Wg2, bg2,
                       Wh3, Ws3, bs3, Wmu3, Wg3, bg3,
                       A, B, VA, VB, out);
}

// Round 6
// 2159.951 us; speedup vs baseline: 1.5606x; 1.5606x over previous
//
#include <hip/hip_runtime.h>
#include <cstddef>

#define EN 800000
#define VN 50000

// Forced-VMEM broadcast load: opaque VGPR zero defeats uniformity analysis,
// so weight reads become global_load_dwordx4 (vmcnt-counted, pipelineable,
// L1/L2-hit) instead of s_load (SMEM out-of-order returns force lgkmcnt(0)
// drains -> no pipelining). z==0 always.
__device__ __forceinline__ float4 ld4(const float* p, int z) {
    return *(const float4*)(p + z);
}
__device__ __forceinline__ float ld1(const float* p, int z) {
    return p[z];
}

// =====================================================================
// node_pre:
//   A[v][j]      = s[v] @ Ws1[0:64]      B[v][j] = s[v] @ Ws1[64:128]
//   VA[v][h*3+r] = V[v] @ Wh1[0:8]       VB      = V[v] @ Wh1[8:16]   (h-major)
// =====================================================================
__global__ __launch_bounds__(256) void node_pre(
    const float* __restrict__ s, const float* __restrict__ V,
    const float* __restrict__ Wh1, const float* __restrict__ Ws1,
    float* __restrict__ A, float* __restrict__ B,
    float* __restrict__ VA, float* __restrict__ VB)
{
    const int tid  = threadIdx.x;
    const int lane = tid & 63;
    const int wv   = __builtin_amdgcn_readfirstlane(tid >> 6);

    float w[128];
    #pragma unroll
    for (int k = 0; k < 128; ++k) w[k] = Ws1[k * 64 + lane];

    const int hv = (lane < 51) ? (lane / 3) : 0;
    const int rv = (lane < 51) ? (lane % 3) : 0;
    float whA[8], whB[8];
    #pragma unroll
    for (int d = 0; d < 8; ++d) {
        whA[d] = Wh1[d * 17 + hv];
        whB[d] = Wh1[(8 + d) * 17 + hv];
    }

    const int nwaves = gridDim.x * 4;
    for (int v = blockIdx.x * 4 + wv; v < VN; v += nwaves) {
        const float* sv = s + (size_t)v * 64;
        float a = 0.f, b = 0.f;
        #pragma unroll
        for (int k = 0; k < 64; ++k) {
            float sk = sv[k];
            a += sk * w[k];
            b += sk * w[64 + k];
        }
        A[(size_t)v * 64 + lane] = a;
        B[(size_t)v * 64 + lane] = b;

        const float* vrow = V + (size_t)v * 24 + rv * 8;
        float va = 0.f, vb = 0.f;
        #pragma unroll
        for (int d = 0; d < 8; ++d) {
            float x = vrow[d];
            va += x * whA[d];
            vb += x * whB[d];
        }
        if (lane < 51) {
            VA[(size_t)v * 52 + lane] = va;
            VB[(size_t)v * 52 + lane] = vb;
        }
    }
}

// =====================================================================
// edge_kernel: one thread per edge.
//  - Per-edge multiplicand vectors live in the thread's LDS column
//    wbuf[k][lane] (stride-1 across lanes, conflict-free, no barriers) so
//    ALL matmul k-loops are ROLLED (runtime k, zero spill, tiny I-footprint).
//  - Weights: forced-VMEM broadcast (ld4 + opaque z) -> global_load_dwordx4
//    with SGPR base + imm offset; vmcnt-pipelined, L1-resident per phase.
//  - acc stored to LDS PRE-relu; gate reads pre-relu; next layer's k-loop
//    applies relu on the fly (uniform-k select). No global scratch.
//  LDS: 4 waves * 72 * 64 * 4B = 72 KB -> 2 blocks/CU (8 waves).
// =====================================================================
__global__ __launch_bounds__(256, 2) void edge_kernel(
    const float* __restrict__ s_e, const float* __restrict__ V_e,
    const int* __restrict__ eidx,
    const float* __restrict__ Wh1, const float* __restrict__ Ws1, const float* __restrict__ bs1,
    const float* __restrict__ Wmu1, const float* __restrict__ Wg1, const float* __restrict__ bg1,
    const float* __restrict__ Wh2, const float* __restrict__ Ws2, const float* __restrict__ bs2,
    const float* __restrict__ Wmu2, const float* __restrict__ Wg2, const float* __restrict__ bg2,
    const float* __restrict__ Wh3, const float* __restrict__ Ws3, const float* __restrict__ bs3,
    const float* __restrict__ Wmu3, const float* __restrict__ Wg3, const float* __restrict__ bg3,
    const float* __restrict__ A, const float* __restrict__ B,
    const float* __restrict__ VA, const float* __restrict__ VB,
    float* __restrict__ out)
{
    __shared__ float buf[4][72][64];
    int z;
    asm volatile("v_mov_b32 %0, 0" : "=v"(z));   // opaque zero (VGPR)

    const int tid  = threadIdx.x;
    const int lane = tid & 63;
    const int wv   = tid >> 6;
    float (*wbuf)[64] = buf[wv];

    const int e   = blockIdx.x * 256 + tid;
    const int src = eidx[e];
    const int dst = eidx[EN + e];

    // ---------------- Layer 1: vector path ----------------
    const float ve0 = V_e[(size_t)e * 3 + 0];
    const float ve1 = V_e[(size_t)e * 3 + 1];
    const float ve2 = V_e[(size_t)e * 3 + 2];

    float wv16[17];
    {
        const float* p = Wh1 + 16 * 17;
        #pragma unroll
        for (int q = 0; q < 4; ++q) {
            float4 t = ld4(p + 4 * q, z);
            wv16[4*q] = t.x; wv16[4*q+1] = t.y; wv16[4*q+2] = t.z; wv16[4*q+3] = t.w;
        }
        wv16[16] = ld1(p + 16, z);
    }

    float vmu[24];
    #pragma unroll
    for (int o = 0; o < 24; ++o) vmu[o] = 0.f;

    const float4* qa = (const float4*)(VA + (size_t)src * 52);
    const float4* qb = (const float4*)(VB + (size_t)dst * 52);

    // vn -> wbuf rows 16..32 (row 16+h pairs with Ws1 row 144+h)
    #pragma unroll
    for (int c = 0; c < 4; ++c) {          // h = 4c .. 4c+3 (h-major chunks)
        float4 a0 = qa[3*c], a1 = qa[3*c+1], a2 = qa[3*c+2];
        float4 b0 = qb[3*c], b1 = qb[3*c+1], b2 = qb[3*c+2];
        float av[12] = {a0.x,a0.y,a0.z,a0.w, a1.x,a1.y,a1.z,a1.w, a2.x,a2.y,a2.z,a2.w};
        float bv[12] = {b0.x,b0.y,b0.z,b0.w, b1.x,b1.y,b1.z,b1.w, b2.x,b2.y,b2.z,b2.w};
        #pragma unroll
        for (int i = 0; i < 4; ++i) {
            const int h = 4*c + i;
            float ww = wv16[h];
            float v0 = av[3*i+0] + bv[3*i+0] + ve0 * ww;
            float v1 = av[3*i+1] + bv[3*i+1] + ve1 * ww;
            float v2 = av[3*i+2] + bv[3*i+2] + ve2 * ww;
            wbuf[16 + h][lane] = sqrtf(v0*v0 + v1*v1 + v2*v2 + 1e-8f);
            float4 m0 = ld4(Wmu1 + h * 8, z);
            float4 m1 = ld4(Wmu1 + h * 8 + 4, z);
            vmu[0]  += v0*m0.x; vmu[1]  += v0*m0.y; vmu[2]  += v0*m0.z; vmu[3]  += v0*m0.w;
            vmu[4]  += v0*m1.x; vmu[5]  += v0*m1.y; vmu[6]  += v0*m1.z; vmu[7]  += v0*m1.w;
            vmu[8]  += v1*m0.x; vmu[9]  += v1*m0.y; vmu[10] += v1*m0.z; vmu[11] += v1*m0.w;
            vmu[12] += v1*m1.x; vmu[13] += v1*m1.y; vmu[14] += v1*m1.z; vmu[15] += v1*m1.w;
            vmu[16] += v2*m0.x; vmu[17] += v2*m0.y; vmu[18] += v2*m0.z; vmu[19] += v2*m0.w;
            vmu[20] += v2*m1.x; vmu[21] += v2*m1.y; vmu[22] += v2*m1.z; vmu[23] += v2*m1.w;
        }
    }
    {   // h = 16
        float4 a = qa[12], b = qb[12];
        float ww = wv16[16];
        float v0 = a.x + b.x + ve0 * ww;
        float v1 = a.y + b.y + ve1 * ww;
        float v2 = a.z + b.z + ve2 * ww;
        wbuf[32][lane] = sqrtf(v0*v0 + v1*v1 + v2*v2 + 1e-8f);
        float4 m0 = ld4(Wmu1 + 16 * 8, z);
        float4 m1 = ld4(Wmu1 + 16 * 8 + 4, z);
        vmu[0]  += v0*m0.x; vmu[1]  += v0*m0.y; vmu[2]  += v0*m0.z; vmu[3]  += v0*m0.w;
        vmu[4]  += v0*m1.x; vmu[5]  += v0*m1.y; vmu[6]  += v0*m1.z; vmu[7]  += v0*m1.w;
        vmu[8]  += v1*m0.x; vmu[9]  += v1*m0.y; vmu[10] += v1*m0.z; vmu[11] += v1*m0.w;
        vmu[12] += v1*m1.x; vmu[13] += v1*m1.y; vmu[14] += v1*m1.z; vmu[15] += v1*m1.w;
        vmu[16] += v2*m0.x; vmu[17] += v2*m0.y; vmu[18] += v2*m0.z; vmu[19] += v2*m0.w;
        vmu[20] += v2*m1.x; vmu[21] += v2*m1.y; vmu[22] += v2*m1.z; vmu[23] += v2*m1.w;
    }

    // s_e -> wbuf rows 0..15 (row k pairs with Ws1 row 128+k)
    {
        const float4* ps = (const float4*)(s_e + (size_t)e * 16);
        #pragma unroll
        for (int q = 0; q < 4; ++q) {
            float4 t = ps[q];
            wbuf[4*q+0][lane] = t.x; wbuf[4*q+1][lane] = t.y;
            wbuf[4*q+2][lane] = t.z; wbuf[4*q+3][lane] = t.w;
        }
    }

    // ---------------- Layer 1: scalar path ----------------
    float acc[64];
    {
        const float4* fa = (const float4*)(A + (size_t)src * 64);
        const float4* fb = (const float4*)(B + (size_t)dst * 64);
        #pragma unroll
        for (int q = 0; q < 16; ++q) {
            float4 ta = fa[q], tb = fb[q];
            float4 bb = ld4(bs1 + 4 * q, z);
            acc[4*q+0] = ta.x + tb.x + bb.x;
            acc[4*q+1] = ta.y + tb.y + bb.y;
            acc[4*q+2] = ta.z + tb.z + bb.z;
            acc[4*q+3] = ta.w + tb.w + bb.w;
        }
    }
    // rolled over 33 rows: m from LDS column, weights from VMEM broadcast
    #pragma unroll 2
    for (int k = 0; k < 33; ++k) {
        float m = wbuf[k][lane];
        const float* wr = Ws1 + (128 + k) * 64;
        #pragma unroll
        for (int q = 0; q < 16; ++q) {
            float4 w = ld4(wr + 4 * q, z);
            acc[4*q+0] += m * w.x; acc[4*q+1] += m * w.y;
            acc[4*q+2] += m * w.z; acc[4*q+3] += m * w.w;
        }
    }

    // store PRE-relu acc -> rows 0..63; gate1 rolled (reads pre-relu)
    #pragma unroll
    for (int j = 0; j < 64; ++j) wbuf[j][lane] = acc[j];

    float Vv[24];
    {
        float g[8];
        float4 b0 = ld4(bg1, z), b1 = ld4(bg1 + 4, z);
        g[0]=b0.x; g[1]=b0.y; g[2]=b0.z; g[3]=b0.w;
        g[4]=b1.x; g[5]=b1.y; g[6]=b1.z; g[7]=b1.w;
        #pragma unroll 2
        for (int k = 0; k < 64; ++k) {
            float m = wbuf[k][lane];
            float4 wa = ld4(Wg1 + k * 8, z), wb = ld4(Wg1 + k * 8 + 4, z);
            g[0] += m*wa.x; g[1] += m*wa.y; g[2] += m*wa.z; g[3] += m*wa.w;
            g[4] += m*wb.x; g[5] += m*wb.y; g[6] += m*wb.z; g[7] += m*wb.w;
        }
        #pragma unroll
        for (int o = 0; o < 8; ++o) {
            float gg = 1.f / (1.f + __expf(-g[o]));
            Vv[o] = vmu[o]*gg; Vv[8+o] = vmu[8+o]*gg; Vv[16+o] = vmu[16+o]*gg;
        }
    }

    // ---------------- Layers 2 & 3 (identical; relu applied by consumer) ---
    #pragma unroll 1
    for (int t = 0; t < 2; ++t) {
        const float* Wh  = t ? Wh3  : Wh2;
        const float* Ws  = t ? Ws3  : Ws2;
        const float* bs  = t ? bs3  : bs2;
        const float* Wmu = t ? Wmu3 : Wmu2;
        const float* Wg  = t ? Wg3  : Wg2;
        const float* bg  = t ? bg3  : bg2;

        // vector path: Vh = Vv @ Wh (row-broadcast form, float4 weight rows)
        float v0a[8], v1a[8], v2a[8];
        #pragma unroll
        for (int h = 0; h < 8; ++h) { v0a[h]=0.f; v1a[h]=0.f; v2a[h]=0.f; }
        #pragma unroll
        for (int d = 0; d < 8; ++d) {
            float4 w0 = ld4(Wh + d * 8, z), w1 = ld4(Wh + d * 8 + 4, z);
            float a0 = Vv[d], a1 = Vv[8+d], a2 = Vv[16+d];
            v0a[0]+=a0*w0.x; v0a[1]+=a0*w0.y; v0a[2]+=a0*w0.z; v0a[3]+=a0*w0.w;
            v0a[4]+=a0*w1.x; v0a[5]+=a0*w1.y; v0a[6]+=a0*w1.z; v0a[7]+=a0*w1.w;
            v1a[0]+=a1*w0.x; v1a[1]+=a1*w0.y; v1a[2]+=a1*w0.z; v1a[3]+=a1*w0.w;
            v1a[4]+=a1*w1.x; v1a[5]+=a1*w1.y; v1a[6]+=a1*w1.z; v1a[7]+=a1*w1.w;
            v2a[0]+=a2*w0.x; v2a[1]+=a2*w0.y; v2a[2]+=a2*w0.z; v2a[3]+=a2*w0.w;
            v2a[4]+=a2*w1.x; v2a[5]+=a2*w1.y; v2a[6]+=a2*w1.z; v2a[7]+=a2*w1.w;
        }
        float vmu2[24];
        #pragma unroll
        for (int o = 0; o < 24; ++o) vmu2[o] = 0.f;
        #pragma unroll
        for (int h = 0; h < 8; ++h) {
            wbuf[64 + h][lane] =
                sqrtf(v0a[h]*v0a[h] + v1a[h]*v1a[h] + v2a[h]*v2a[h] + 1e-8f);
            float4 m0 = ld4(Wmu + h * 8, z), m1 = ld4(Wmu + h * 8 + 4, z);
            vmu2[0]  += v0a[h]*m0.x; vmu2[1]  += v0a[h]*m0.y; vmu2[2]  += v0a[h]*m0.z; vmu2[3]  += v0a[h]*m0.w;
            vmu2[4]  += v0a[h]*m1.x; vmu2[5]  += v0a[h]*m1.y; vmu2[6]  += v0a[h]*m1.z; vmu2[7]  += v0a[h]*m1.w;
            vmu2[8]  += v1a[h]*m0.x; vmu2[9]  += v1a[h]*m0.y; vmu2[10] += v1a[h]*m0.z; vmu2[11] += v1a[h]*m0.w;
            vmu2[12] += v1a[h]*m1.x; vmu2[13] += v1a[h]*m1.y; vmu2[14] += v1a[h]*m1.z; vmu2[15] += v1a[h]*m1.w;
            vmu2[16] += v2a[h]*m0.x; vmu2[17] += v2a[h]*m0.y; vmu2[18] += v2a[h]*m0.z; vmu2[19] += v2a[h]*m0.w;
            vmu2[20] += v2a[h]*m1.x; vmu2[21] += v2a[h]*m1.y; vmu2[22] += v2a[h]*m1.z; vmu2[23] += v2a[h]*m1.w;
        }

        // scalar path: rolled over 72 rows (relu rows 0..63 on the fly)
        #pragma unroll
        for (int q = 0; q < 16; ++q) {
            float4 bb = ld4(bs + 4 * q, z);
            acc[4*q]=bb.x; acc[4*q+1]=bb.y; acc[4*q+2]=bb.z; acc[4*q+3]=bb.w;
        }
        #pragma unroll 2
        for (int k = 0; k < 72; ++k) {
            float m = wbuf[k][lane];
            if (k < 64) m = fmaxf(m, 0.f);   // uniform-k select (pre-relu stored)
            const float* wr = Ws + k * 64;
            #pragma unroll
            for (int q = 0; q < 16; ++q) {
                float4 w = ld4(wr + 4 * q, z);
                acc[4*q+0] += m * w.x; acc[4*q+1] += m * w.y;
                acc[4*q+2] += m * w.z; acc[4*q+3] += m * w.w;
            }
        }

        // store PRE-relu; gate rolled; Vv update
        #pragma unroll
        for (int j = 0; j < 64; ++j) wbuf[j][lane] = acc[j];
        float g[8];
        {
            float4 b0 = ld4(bg, z), b1 = ld4(bg + 4, z);
            g[0]=b0.x; g[1]=b0.y; g[2]=b0.z; g[3]=b0.w;
            g[4]=b1.x; g[5]=b1.y; g[6]=b1.z; g[7]=b1.w;
        }
        #pragma unroll 2
        for (int k = 0; k < 64; ++k) {
            float m = wbuf[k][lane];
            float4 wa = ld4(Wg + k * 8, z), wb = ld4(Wg + k * 8 + 4, z);
            g[0] += m*wa.x; g[1] += m*wa.y; g[2] += m*wa.z; g[3] += m*wa.w;
            g[4] += m*wb.x; g[5] += m*wb.y; g[6] += m*wb.z; g[7] += m*wb.w;
        }
        #pragma unroll
        for (int o = 0; o < 8; ++o) {
            float gg = 1.f / (1.f + __expf(-g[o]));
            Vv[o] = vmu2[o]*gg; Vv[8+o] = vmu2[8+o]*gg; Vv[16+o] = vmu2[16+o]*gg;
        }
    }

    // ---------------- outputs: s3 = acc (layer 3 has no relu), V3 = Vv ----
    float4* po = (float4*)(out + (size_t)e * 64);
    #pragma unroll
    for (int q = 0; q < 16; ++q) {
        float4 tq; tq.x = acc[4*q]; tq.y = acc[4*q+1]; tq.z = acc[4*q+2]; tq.w = acc[4*q+3];
        po[q] = tq;
    }
    float4* pv = (float4*)(out + (size_t)EN * 64 + (size_t)e * 24);
    #pragma unroll
    for (int q = 0; q < 6; ++q) {
        float4 tq; tq.x = Vv[4*q]; tq.y = Vv[4*q+1]; tq.z = Vv[4*q+2]; tq.w = Vv[4*q+3];
        pv[q] = tq;
    }
}

extern "C" void kernel_launch(void* const* d_in, const int* in_sizes, int n_in,
                              void* d_out, int out_size, void* d_ws, size_t ws_size,
                              hipStream_t stream)
{
    const float* s    = (const float*)d_in[0];
    const float* V    = (const float*)d_in[1];
    const float* s_e  = (const float*)d_in[2];
    const float* V_e  = (const float*)d_in[3];
    const int*   eidx = (const int*)d_in[4];
    const float* Wh1 = (const float*)d_in[5];
    const float* Ws1 = (const float*)d_in[6];
    const float* bs1 = (const float*)d_in[7];
    const float* Wmu1= (const float*)d_in[8];
    const float* Wg1 = (const float*)d_in[9];
    const float* bg1 = (const float*)d_in[10];
    const float* Wh2 = (const float*)d_in[11];
    const float* Ws2 = (const float*)d_in[12];
    const float* bs2 = (const float*)d_in[13];
    const float* Wmu2= (const float*)d_in[14];
    const float* Wg2 = (const float*)d_in[15];
    const float* bg2 = (const float*)d_in[16];
    const float* Wh3 = (const float*)d_in[17];
    const float* Ws3 = (const float*)d_in[18];
    const float* bs3 = (const float*)d_in[19];
    const float* Wmu3= (const float*)d_in[20];
    const float* Wg3 = (const float*)d_in[21];
    const float* bg3 = (const float*)d_in[22];

    float* ws  = (float*)d_ws;
    float* A   = ws;                      // 50000*64
    float* B   = A + 3200000;             // 50000*64
    float* VA  = B + 3200000;             // 50000*52 (h-major, padded)
    float* VB  = VA + 2600000;            // 50000*52
    float* out = (float*)d_out;

    hipLaunchKernelGGL(node_pre, dim3(512), dim3(256), 0, stream,
                       s, V, Wh1, Ws1, A, B, VA, VB);
    hipLaunchKernelGGL(edge_kernel, dim3(EN / 256), dim3(256), 0, stream,
                       s_e, V_e, eidx,
                       Wh1, Ws1, bs1, Wmu1, Wg1, bg1,
                       Wh2, Ws2, bs2, Wmu2, Wg2, bg2,
                       Wh3, Ws3, bs3, Wmu3, Wg3, bg3,
                       A, B, VA, VB, out);
}